// Round 9
// baseline (74.704 us; speedup 1.0000x reference)
//
#include <hip/hip_runtime.h>

typedef short  bf16x8 __attribute__((ext_vector_type(8)));
typedef float  f32x4  __attribute__((ext_vector_type(4)));

#define LSTR  72      // ushort elems per LDS row (144 B, 16B-multiple)
#define LROWS 70
#define NCHK  18      // float4 chunks per staged row

static __device__ __forceinline__ unsigned int rne16(float f) {
    unsigned int u = __float_as_uint(f);
    return (u + 0x7FFFu + ((u >> 16) & 1u)) >> 16;   // fp32 -> bf16 RNE
}

// 64x64 output tile per 256-thread block. LDS holds 70x72 bf16 input
// (tile col c <-> global col x0-4+c). Per weight-row dy:
// D(16x16) += A(16x32) * B(32x16), A = input rows (ds_read_b128 direct),
// B[u][j] = w[dy][u-j-1] (banded), prebuilt per-lane in registers.
__global__ __launch_bounds__(256)
void conv7x7_mfma(const float* __restrict__ x, const float* __restrict__ w,
                  float* __restrict__ out) {
    __shared__ unsigned short tile[LROWS * LSTR];   // 10080 B

    const int W = 512, H = 512;
    const int bi  = blockIdx.x;
    const int n   = bi >> 6;
    const int rem = bi & 63;
    const int y0  = (rem >> 3) * 64;
    const int x0  = (rem & 7) * 64;

    const float* xn = x + (size_t)n * (H * W);
    float*       on = out + (size_t)n * (H * W);

    const int t    = threadIdx.x;
    const int l    = t & 63;
    const int wv   = t >> 6;      // wave id -> tile-row to
    const int l15  = l & 15;      // A-row / B-col / D-col index
    const int lk   = l >> 4;      // k-group
    const int u0   = lk * 8;

    // Wave-uniform weights (SGPR)
    float wr[49];
#pragma unroll
    for (int i = 0; i < 49; ++i) wr[i] = w[i];

    // ---- Build B fragments: lane holds B[u0+q][j=l15], q=0..7, per dy ----
    bf16x8 Bf[7];
#pragma unroll
    for (int dy = 0; dy < 7; ++dy) {
        union { unsigned int u[4]; bf16x8 v; } bb;
#pragma unroll
        for (int qp = 0; qp < 4; ++qp) {
            unsigned int half[2];
#pragma unroll
            for (int h = 0; h < 2; ++h) {
                const int q = qp * 2 + h;
                const int d = u0 + q - l15 - 1;    // weight col dx
                float val = 0.f;
#pragma unroll
                for (int dd = 0; dd < 7; ++dd)
                    val = (d == dd) ? wr[dy * 7 + dd] : val;
                half[h] = rne16(val);
            }
            bb.u[qp] = half[0] | (half[1] << 16);
        }
        Bf[dy] = bb.v;
    }

    // ---- Stage 70x72 fp32 -> bf16(RNE) into LDS ----
#pragma unroll
    for (int k = 0; k < 5; ++k) {
        const int idx = t + 256 * k;
        if (k < 4 || idx < LROWS * NCHK) {
            const int r  = idx / NCHK;
            const int cc = idx - r * NCHK;
            const int gr = y0 - 3 + r;
            const int gc = x0 - 4 + 4 * cc;        // 16B-aligned, full-or-zero
            float4 v = make_float4(0.f, 0.f, 0.f, 0.f);
            if (gr >= 0 && gr < H && gc >= 0 && gc <= W - 4)
                v = *reinterpret_cast<const float4*>(&xn[(size_t)gr * W + gc]);
            const unsigned int p0 = rne16(v.x) | (rne16(v.y) << 16);
            const unsigned int p1 = rne16(v.z) | (rne16(v.w) << 16);
            *reinterpret_cast<uint2*>(&tile[r * LSTR + 4 * cc]) =
                make_uint2(p0, p1);
        }
    }
    __syncthreads();

    // ---- Compute: wave wv owns tiles (to=wv, jo=0..3) ----
    f32x4 acc[4];
#pragma unroll
    for (int jo = 0; jo < 4; ++jo) {
        f32x4 a = {0.f, 0.f, 0.f, 0.f};
        acc[jo] = a;
    }

#pragma unroll
    for (int jo = 0; jo < 4; ++jo) {
#pragma unroll
        for (int dy = 0; dy < 7; ++dy) {
            const int row = wv * 16 + l15 + dy;          // A row (tile coords)
            const bf16x8 a = *reinterpret_cast<const bf16x8*>(
                &tile[row * LSTR + jo * 16 + u0]);       // 16B-aligned b128
            acc[jo] = __builtin_amdgcn_mfma_f32_16x16x32_bf16(a, Bf[dy], acc[jo],
                                                              0, 0, 0);
        }
    }

    // ---- Store: D col = l15, row = lk*4 + rr (m89-verified C/D layout) ----
#pragma unroll
    for (int jo = 0; jo < 4; ++jo) {
#pragma unroll
        for (int rr = 0; rr < 4; ++rr) {
            const int gr = y0 + wv * 16 + lk * 4 + rr;
            const int gc = x0 + jo * 16 + l15;
            on[(size_t)gr * W + gc] = acc[jo][rr];
        }
    }
}

extern "C" void kernel_launch(void* const* d_in, const int* in_sizes, int n_in,
                              void* d_out, int out_size, void* d_ws, size_t ws_size,
                              hipStream_t stream) {
    const float* x = (const float*)d_in[0];
    const float* w = (const float*)d_in[1];
    float* out = (float*)d_out;

    const int nblocks = 128 * 64;   // 8192 blocks x 256 threads
    conv7x7_mfma<<<nblocks, 256, 0, stream>>>(x, w, out);
}

// Round 10
// 69.001 us; speedup vs baseline: 1.0826x; 1.0826x over previous
//
#include <hip/hip_runtime.h>

typedef short  bf16x8 __attribute__((ext_vector_type(8)));
typedef float  f32x4  __attribute__((ext_vector_type(4)));

#define LSTR  72      // ushort elems per LDS row (144 B, 16B-multiple)
#define LROWS 70
#define NCHK  18      // float4 chunks per staged row

static __device__ __forceinline__ unsigned int rne16(float f) {
    unsigned int u = __float_as_uint(f);
    return (u + 0x7FFFu + ((u >> 16) & 1u)) >> 16;   // fp32 -> bf16 RNE
}

// ---- Setup: build banded-B fragments once into ws (7 dy x 64 lanes x 16B) ----
// B[u][j] = w[dy][u-j-1]; lane l holds B[u0+q][j=l&15], q=0..7, u0=(l>>4)*8.
__global__ void build_bfrag(const float* __restrict__ w, bf16x8* __restrict__ ws) {
    const int l   = threadIdx.x;      // 64 threads
    const int l15 = l & 15;
    const int u0  = (l >> 4) * 8;
#pragma unroll
    for (int dy = 0; dy < 7; ++dy) {
        union { unsigned int u[4]; bf16x8 v; } bb;
#pragma unroll
        for (int qp = 0; qp < 4; ++qp) {
            unsigned int half[2];
#pragma unroll
            for (int h = 0; h < 2; ++h) {
                const int d = u0 + qp * 2 + h - l15 - 1;     // weight col dx
                const float val = (d >= 0 && d < 7) ? w[dy * 7 + d] : 0.f;
                half[h] = rne16(val);
            }
            bb.u[qp] = half[0] | (half[1] << 16);
        }
        ws[dy * 64 + l] = bb.v;
    }
}

// ---- Main: 64x64 output tile per 256-thread block, bf16 MFMA stencil ----
__global__ __launch_bounds__(256)
void conv7x7_mfma(const float* __restrict__ x, const bf16x8* __restrict__ Bws,
                  float* __restrict__ out) {
    __shared__ unsigned short tile[LROWS * LSTR];   // 10080 B

    const int W = 512, H = 512;
    const int bi  = blockIdx.x;
    const int n   = bi >> 6;
    const int rem = bi & 63;
    const int y0  = (rem >> 3) * 64;
    const int x0  = (rem & 7) * 64;

    const float* xn = x + (size_t)n * (H * W);
    float*       on = out + (size_t)n * (H * W);

    const int t    = threadIdx.x;
    const int l    = t & 63;
    const int wv   = t >> 6;      // wave id -> tile-row
    const int l15  = l & 15;
    const int lk   = l >> 4;
    const int u0   = lk * 8;

    // Load prebuilt B fragments (L2-resident 7 KB broadcast)
    bf16x8 Bf[7];
#pragma unroll
    for (int dy = 0; dy < 7; ++dy) Bf[dy] = Bws[dy * 64 + l];

    // ---- Stage 70x72 fp32 -> bf16(RNE) into LDS ----
#pragma unroll
    for (int k = 0; k < 5; ++k) {
        const int idx = t + 256 * k;
        if (k < 4 || idx < LROWS * NCHK) {
            const int r  = idx / NCHK;
            const int cc = idx - r * NCHK;
            const int gr = y0 - 3 + r;
            const int gc = x0 - 4 + 4 * cc;        // 16B-aligned, full-or-zero
            float4 v = make_float4(0.f, 0.f, 0.f, 0.f);
            if (gr >= 0 && gr < H && gc >= 0 && gc <= W - 4)
                v = *reinterpret_cast<const float4*>(&xn[(size_t)gr * W + gc]);
            const unsigned int p0 = rne16(v.x) | (rne16(v.y) << 16);
            const unsigned int p1 = rne16(v.z) | (rne16(v.w) << 16);
            *reinterpret_cast<uint2*>(&tile[r * LSTR + 4 * cc]) =
                make_uint2(p0, p1);
        }
    }
    __syncthreads();

    // ---- Compute: wave wv owns tiles (to=wv, jo=0..3) ----
    f32x4 acc[4];
#pragma unroll
    for (int jo = 0; jo < 4; ++jo) {
        f32x4 a = {0.f, 0.f, 0.f, 0.f};
        acc[jo] = a;
    }

#pragma unroll
    for (int jo = 0; jo < 4; ++jo) {
#pragma unroll
        for (int dy = 0; dy < 7; ++dy) {
            const int row = wv * 16 + l15 + dy;          // A row (tile coords)
            const bf16x8 a = *reinterpret_cast<const bf16x8*>(
                &tile[row * LSTR + jo * 16 + u0]);       // 16B-aligned b128
            acc[jo] = __builtin_amdgcn_mfma_f32_16x16x32_bf16(a, Bf[dy], acc[jo],
                                                              0, 0, 0);
        }
    }

    // ---- Store: D col = l15, row = lk*4 + rr (m89-verified C/D layout) ----
#pragma unroll
    for (int jo = 0; jo < 4; ++jo) {
#pragma unroll
        for (int rr = 0; rr < 4; ++rr) {
            const int gr = y0 + wv * 16 + lk * 4 + rr;
            const int gc = x0 + jo * 16 + l15;
            on[(size_t)gr * W + gc] = acc[jo][rr];
        }
    }
}

extern "C" void kernel_launch(void* const* d_in, const int* in_sizes, int n_in,
                              void* d_out, int out_size, void* d_ws, size_t ws_size,
                              hipStream_t stream) {
    const float* x = (const float*)d_in[0];
    const float* w = (const float*)d_in[1];
    float* out = (float*)d_out;
    bf16x8* bws = (bf16x8*)d_ws;

    build_bfrag<<<1, 64, 0, stream>>>(w, bws);

    const int nblocks = 128 * 64;   // 8192 blocks x 256 threads
    conv7x7_mfma<<<nblocks, 256, 0, stream>>>(x, bws, out);
}

// Round 11
// 63.114 us; speedup vs baseline: 1.1836x; 1.0933x over previous
//
#include <hip/hip_runtime.h>

typedef short  bf16x8 __attribute__((ext_vector_type(8)));
typedef float  f32x4  __attribute__((ext_vector_type(4)));

#define LSTR  72      // ushort elems per LDS row (144 B)
#define LROWS 70
#define NCHK  18      // float4 chunks per staged row
#define CHT   (LROWS * NCHK)   // 1260
#define NTILE 4       // x-adjacent 64x64 tiles per block

static __device__ __forceinline__ unsigned int rne16(float f) {
    unsigned int u = __float_as_uint(f);
    return (u + 0x7FFFu + ((u >> 16) & 1u)) >> 16;   // fp32 -> bf16 RNE
}

// ---- Setup: banded-B fragments once into ws (7 dy x 64 lanes x 16B) ----
__global__ void build_bfrag(const float* __restrict__ w, bf16x8* __restrict__ ws) {
    const int l   = threadIdx.x;      // 64 threads
    const int l15 = l & 15;
    const int u0  = (l >> 4) * 8;
#pragma unroll
    for (int dy = 0; dy < 7; ++dy) {
        union { unsigned int u[4]; bf16x8 v; } bb;
#pragma unroll
        for (int qp = 0; qp < 4; ++qp) {
            unsigned int half[2];
#pragma unroll
            for (int h = 0; h < 2; ++h) {
                const int d = u0 + qp * 2 + h - l15 - 1;     // weight col dx
                const float val = (d >= 0 && d < 7) ? w[dy * 7 + d] : 0.f;
                half[h] = rne16(val);
            }
            bb.u[qp] = half[0] | (half[1] << 16);
        }
        ws[dy * 64 + l] = bb.v;
    }
}

// ---- Main: 4-tile pipelined block (256 thr), bf16 MFMA stencil ----
__global__ __launch_bounds__(256)
void conv7x7_mfma(const float* __restrict__ x, const bf16x8* __restrict__ Bws,
                  float* __restrict__ out) {
    __shared__ unsigned short tile[2][LROWS * LSTR];   // 2 x 10080 B

    const int W = 512, H = 512;
    const int bi  = blockIdx.x;          // n(7) | ty(3) | g(1)
    const int n   = bi >> 4;
    const int ty  = (bi >> 1) & 7;
    const int g   = bi & 1;
    const int y0  = ty * 64;
    const int x0g = g * 256;             // 4 tiles: x0g + 64k

    const float* xn = x + (size_t)n * (H * W);
    float*       on = out + (size_t)n * (H * W);

    const int t   = threadIdx.x;
    const int l   = t & 63;
    const int wv  = t >> 6;
    const int l15 = l & 15;
    const int lk  = l >> 4;
    const int u0  = lk * 8;

    // Prebuilt B fragments (L2-resident broadcast)
    bf16x8 Bf[7];
#pragma unroll
    for (int dy = 0; dy < 7; ++dy) Bf[dy] = Bws[dy * 64 + l];

    // k-invariant staging descriptors
    int  d_roff[5], d_loff[5], d_xoff[5];
    bool d_rok[5], d_on[5];
#pragma unroll
    for (int it = 0; it < 5; ++it) {
        const int idx = t + 256 * it;
        const int r   = idx / NCHK;
        const int cc  = idx - r * NCHK;
        const int gr  = y0 - 3 + r;
        d_on[it]   = (idx < CHT);
        d_rok[it]  = (idx < CHT) && (gr >= 0) && (gr < H);
        d_xoff[it] = x0g - 4 + 4 * cc;
        d_roff[it] = gr * W;
        d_loff[it] = r * LSTR + 4 * cc;
    }

    float4 sreg[5];

#define ISSUE(k_)                                                              \
    {                                                                          \
        _Pragma("unroll")                                                      \
        for (int it = 0; it < 5; ++it) {                                       \
            const int gc = d_xoff[it] + 64 * (k_);                             \
            float4 v = make_float4(0.f, 0.f, 0.f, 0.f);                        \
            if (d_rok[it] && gc >= 0 && gc <= W - 4)                           \
                v = *reinterpret_cast<const float4*>(&xn[d_roff[it] + gc]);    \
            sreg[it] = v;                                                      \
        }                                                                      \
    }

#define LDSWRITE(buf_)                                                         \
    {                                                                          \
        _Pragma("unroll")                                                      \
        for (int it = 0; it < 5; ++it) {                                       \
            if (d_on[it]) {                                                    \
                const unsigned p0 = rne16(sreg[it].x) | (rne16(sreg[it].y) << 16); \
                const unsigned p1 = rne16(sreg[it].z) | (rne16(sreg[it].w) << 16); \
                *reinterpret_cast<uint2*>(&tile[buf_][d_loff[it]]) =           \
                    make_uint2(p0, p1);                                        \
            }                                                                  \
        }                                                                      \
    }

    ISSUE(0)

#pragma unroll
    for (int k = 0; k < NTILE; ++k) {
        LDSWRITE(k & 1)            // waits vmcnt for tile k's loads
        __syncthreads();
        if (k + 1 < NTILE) ISSUE(k + 1)   // in flight during compute(k)

        const int xk = x0g + 64 * k;
#pragma unroll
        for (int jo = 0; jo < 4; ++jo) {
            f32x4 acc = {0.f, 0.f, 0.f, 0.f};
#pragma unroll
            for (int dy = 0; dy < 7; ++dy) {
                const int row = wv * 16 + l15 + dy;
                const bf16x8 a = *reinterpret_cast<const bf16x8*>(
                    &tile[k & 1][row * LSTR + jo * 16 + u0]);
                acc = __builtin_amdgcn_mfma_f32_16x16x32_bf16(a, Bf[dy], acc,
                                                              0, 0, 0);
            }
#pragma unroll
            for (int rr = 0; rr < 4; ++rr) {
                const int gr = y0 + wv * 16 + lk * 4 + rr;
                on[(size_t)gr * W + xk + jo * 16 + l15] = acc[rr];
            }
        }
        // barrier at top of next iter (LDSWRITE->syncthreads) separates
        // compute(k) reads from iter k+2 writes to the same buffer.
    }

#undef ISSUE
#undef LDSWRITE
}

extern "C" void kernel_launch(void* const* d_in, const int* in_sizes, int n_in,
                              void* d_out, int out_size, void* d_ws, size_t ws_size,
                              hipStream_t stream) {
    const float* x = (const float*)d_in[0];
    const float* w = (const float*)d_in[1];
    float* out = (float*)d_out;
    bf16x8* bws = (bf16x8*)d_ws;

    build_bfrag<<<1, 64, 0, stream>>>(w, bws);

    const int nblocks = 128 * 8 * 2;   // 2048 blocks x 256 threads
    conv7x7_mfma<<<nblocks, 256, 0, stream>>>(x, bws, out);
}

// Round 14
// 58.400 us; speedup vs baseline: 1.2792x; 1.0807x over previous
//
#include <hip/hip_runtime.h>

typedef short  bf16x8 __attribute__((ext_vector_type(8)));
typedef float  f32x4  __attribute__((ext_vector_type(4)));

#define LSTR  72      // ushort elems per LDS row (144 B)
#define LROWS 70
#define NCHK  18      // float4 chunks per staged row
#define CHT   (LROWS * NCHK)   // 1260
#define NTILE 4       // x-adjacent 64x64 tiles per block
#define TSZ   (LROWS * LSTR)   // 5040 ushorts
// Lane 63 (l15=15,lk=3) at jo=3,dy=6,wv=3 reads tile[buf][5040..5047] — one
// b128 past the data. B rows u>=24 are structurally zero, so ANY finite pad
// works; it must be ZEROED to avoid NaN/Inf * 0 (R12 failed on stale LDS).
#define TPAD  8

static __device__ __forceinline__ unsigned int rne16(float f) {
    unsigned int u = __float_as_uint(f);
    return (u + 0x7FFFu + ((u >> 16) & 1u)) >> 16;   // fp32 -> bf16 RNE
}

// ---- Setup: banded-B fragments once into ws (7 dy x 64 lanes x 16B) ----
__global__ void build_bfrag(const float* __restrict__ w, bf16x8* __restrict__ ws) {
    const int l   = threadIdx.x;      // 64 threads
    const int l15 = l & 15;
    const int u0  = (l >> 4) * 8;
#pragma unroll
    for (int dy = 0; dy < 7; ++dy) {
        union { unsigned int u[4]; bf16x8 v; } bb;
#pragma unroll
        for (int qp = 0; qp < 4; ++qp) {
            unsigned int half[2];
#pragma unroll
            for (int h = 0; h < 2; ++h) {
                const int d = u0 + qp * 2 + h - l15 - 1;     // weight col dx
                const float val = (d >= 0 && d < 7) ? w[dy * 7 + d] : 0.f;
                half[h] = rne16(val);
            }
            bb.u[qp] = half[0] | (half[1] << 16);
        }
        ws[dy * 64 + l] = bb.v;
    }
}

// ---- Main: 4-tile pipelined block (R11 schedule: ISSUE after barrier) ----
__global__ __launch_bounds__(256)
void conv7x7_mfma(const float* __restrict__ x, const bf16x8* __restrict__ Bws,
                  float* __restrict__ out) {
    __shared__ unsigned short tile[2][TSZ + TPAD];

    const int W = 512, H = 512;
    // XCD-aware bijective swizzle (2048 blocks % 8 XCDs == 0): consecutive
    // logical tiles (shared halo rows) stay on one XCD's L2.
    const int raw = blockIdx.x;
    const int bi  = (raw & 7) * 256 + (raw >> 3);
    const int n   = bi >> 4;             // n(7) | ty(3) | g(1)
    const int ty  = (bi >> 1) & 7;
    const int g   = bi & 1;
    const int y0  = ty * 64;
    const int x0g = g * 256;             // 4 tiles: x0g + 64k

    const float* xn = x + (size_t)n * (H * W);
    float*       on = out + (size_t)n * (H * W);

    const int t   = threadIdx.x;
    const int l   = t & 63;
    const int wv  = t >> 6;
    const int l15 = l & 15;
    const int lk  = l >> 4;
    const int u0  = lk * 8;

    // Zero the overflow pads (read-only region; before first barrier)
    if (t < TPAD) { tile[0][TSZ + t] = 0; tile[1][TSZ + t] = 0; }

    // Prebuilt B fragments (L2-resident broadcast)
    bf16x8 Bf[7];
#pragma unroll
    for (int dy = 0; dy < 7; ++dy) Bf[dy] = Bws[dy * 64 + l];

    // k-invariant staging descriptors
    int  d_roff[5], d_loff[5], d_xoff[5];
    bool d_rok[5], d_on[5];
#pragma unroll
    for (int it = 0; it < 5; ++it) {
        const int idx = t + 256 * it;
        const int r   = idx / NCHK;
        const int cc  = idx - r * NCHK;
        const int gr  = y0 - 3 + r;
        d_on[it]   = (idx < CHT);
        d_rok[it]  = (idx < CHT) && (gr >= 0) && (gr < H);
        d_xoff[it] = x0g - 4 + 4 * cc;
        d_roff[it] = gr * W;
        d_loff[it] = r * LSTR + 4 * cc;
    }

    float4 sreg[5];

#define ISSUE(k_)                                                              \
    {                                                                          \
        _Pragma("unroll")                                                      \
        for (int it = 0; it < 5; ++it) {                                       \
            const int gc = d_xoff[it] + 64 * (k_);                             \
            float4 v = make_float4(0.f, 0.f, 0.f, 0.f);                        \
            if (d_rok[it] && gc >= 0 && gc <= W - 4)                           \
                v = *reinterpret_cast<const float4*>(&xn[d_roff[it] + gc]);    \
            sreg[it] = v;                                                      \
        }                                                                      \
    }

#define LDSWRITE(buf_)                                                         \
    {                                                                          \
        _Pragma("unroll")                                                      \
        for (int it = 0; it < 5; ++it) {                                       \
            if (d_on[it]) {                                                    \
                const unsigned p0 = rne16(sreg[it].x) | (rne16(sreg[it].y) << 16); \
                const unsigned p1 = rne16(sreg[it].z) | (rne16(sreg[it].w) << 16); \
                *reinterpret_cast<uint2*>(&tile[buf_][d_loff[it]]) =           \
                    make_uint2(p0, p1);                                        \
            }                                                                  \
        }                                                                      \
    }

    ISSUE(0)

#pragma unroll
    for (int k = 0; k < NTILE; ++k) {
        LDSWRITE(k & 1)            // waits vmcnt for tile k's loads
        __syncthreads();
        if (k + 1 < NTILE) ISSUE(k + 1)   // in flight during compute(k)

        const int xk = x0g + 64 * k;
#pragma unroll
        for (int jo = 0; jo < 4; ++jo) {
            f32x4 acc = {0.f, 0.f, 0.f, 0.f};
#pragma unroll
            for (int dy = 0; dy < 7; ++dy) {
                const int row = wv * 16 + l15 + dy;
                const bf16x8 a = *reinterpret_cast<const bf16x8*>(
                    &tile[k & 1][row * LSTR + jo * 16 + u0]);
                acc = __builtin_amdgcn_mfma_f32_16x16x32_bf16(a, Bf[dy], acc,
                                                              0, 0, 0);
            }
#pragma unroll
            for (int rr = 0; rr < 4; ++rr) {
                const int gr = y0 + wv * 16 + lk * 4 + rr;
                on[(size_t)gr * W + xk + jo * 16 + l15] = acc[rr];
            }
        }
        // barrier at top of next iter (LDSWRITE->syncthreads) separates
        // compute(k) reads from iter k+2 writes to the same buffer.
    }

#undef ISSUE
#undef LDSWRITE
}

extern "C" void kernel_launch(void* const* d_in, const int* in_sizes, int n_in,
                              void* d_out, int out_size, void* d_ws, size_t ws_size,
                              hipStream_t stream) {
    const float* x = (const float*)d_in[0];
    const float* w = (const float*)d_in[1];
    float* out = (float*)d_out;
    bf16x8* bws = (bf16x8*)d_ws;

    build_bfrag<<<1, 64, 0, stream>>>(w, bws);

    const int nblocks = 128 * 8 * 2;   // 2048 blocks x 256 threads
    conv7x7_mfma<<<nblocks, 256, 0, stream>>>(x, bws, out);
}

// Round 15
// 48.939 us; speedup vs baseline: 1.5265x; 1.1933x over previous
//
#include <hip/hip_runtime.h>

typedef short  bf16x8 __attribute__((ext_vector_type(8)));
typedef float  f32x4  __attribute__((ext_vector_type(4)));

#define WROWS 22            // 16 output rows + 6 halo
#define WSTR  72            // ushorts per row (144 B, 16B-multiple)
#define WPAD  8             // lane63/jo3 b128 overrun: must be zeroed, finite
#define WSZ   (WROWS * WSTR + WPAD)   // 1592 ushorts = 3184 B (16B-aligned)
#define NCHW  18            // float4 chunks per row
#define CHTW  (WROWS * NCHW)          // 396 chunks per wave-tile

static __device__ __forceinline__ unsigned int rne16(float f) {
    unsigned int u = __float_as_uint(f);
    return (u + 0x7FFFu + ((u >> 16) & 1u)) >> 16;   // fp32 -> bf16 RNE
}

// ---- Setup: banded-B fragments once into ws (7 dy x 64 lanes x 16B) ----
// B[u][j] = w[dy][u-j-1]; rows u >= 23 structurally zero (kills A-read wrap).
__global__ void build_bfrag(const float* __restrict__ w, bf16x8* __restrict__ ws) {
    const int l   = threadIdx.x;      // 64 threads
    const int l15 = l & 15;
    const int u0  = (l >> 4) * 8;
#pragma unroll
    for (int dy = 0; dy < 7; ++dy) {
        union { unsigned int u[4]; bf16x8 v; } bb;
#pragma unroll
        for (int qp = 0; qp < 4; ++qp) {
            unsigned int half[2];
#pragma unroll
            for (int h = 0; h < 2; ++h) {
                const int d = u0 + qp * 2 + h - l15 - 1;     // weight col dx
                const float val = (d >= 0 && d < 7) ? w[dy * 7 + d] : 0.f;
                half[h] = rne16(val);
            }
            bb.u[qp] = half[0] | (half[1] << 16);
        }
        ws[dy * 64 + l] = bb.v;
    }
}

// ---- Main: BARRIER-FREE. Each wave owns a 16x64 output tile and a private
// 22x72 bf16 LDS region. ds_write -> ds_read within one wave needs only
// lgkmcnt ordering (compiler-inserted); no __syncthreads anywhere. ----
__global__ __launch_bounds__(256)
void conv7x7_mfma(const float* __restrict__ x, const bf16x8* __restrict__ Bws,
                  float* __restrict__ out) {
    __shared__ unsigned short lds[4][WSZ];   // 12736 B/block

    const int W = 512, H = 512;
    // XCD-aware bijective swizzle (8192 % 8 == 0)
    const int raw = blockIdx.x;
    const int bi  = (raw & 7) * 1024 + (raw >> 3);
    const int n   = bi >> 6;             // n(7) | ty(3) | tx(3)
    const int ty  = (bi >> 3) & 7;
    const int tx  = bi & 7;

    const float* xn = x + (size_t)n * (H * W);
    float*       on = out + (size_t)n * (H * W);

    const int t   = threadIdx.x;
    const int l   = t & 63;
    const int wv  = t >> 6;
    const int l15 = l & 15;
    const int lk  = l >> 4;
    const int u0  = lk * 8;

    const int y0 = ty * 64 + wv * 16;    // wave's first output row
    const int x0 = tx * 64;              // wave's first output col

    unsigned short* my = lds[wv];        // wave-private region

    // Zero the wave's pad (read-only wrap region; same-wave, no barrier)
    if (l < WPAD) my[WROWS * WSTR + l] = 0;

    // Prebuilt B fragments (L2-resident broadcast)
    bf16x8 Bf[7];
#pragma unroll
    for (int dy = 0; dy < 7; ++dy) Bf[dy] = Bws[dy * 64 + l];

    // ---- Stage the wave's 22x72 tile: fp32 -> bf16(RNE), wave-private ----
    float4 sreg[7];
    int    loff[7];
    bool   act[7];
#pragma unroll
    for (int it = 0; it < 7; ++it) {
        const int idx = l + 64 * it;
        const int r   = idx / NCHW;
        const int cc  = idx - r * NCHW;
        const int gr  = y0 - 3 + r;
        const int gc  = x0 - 4 + 4 * cc;   // 16B-aligned, full-or-zero OOB
        act[it]  = (idx < CHTW);
        loff[it] = r * WSTR + 4 * cc;
        float4 v = make_float4(0.f, 0.f, 0.f, 0.f);
        if (act[it] && gr >= 0 && gr < H && gc >= 0 && gc <= W - 4)
            v = *reinterpret_cast<const float4*>(&xn[(size_t)gr * W + gc]);
        sreg[it] = v;
    }
#pragma unroll
    for (int it = 0; it < 7; ++it) {
        if (act[it]) {
            const unsigned p0 = rne16(sreg[it].x) | (rne16(sreg[it].y) << 16);
            const unsigned p1 = rne16(sreg[it].z) | (rne16(sreg[it].w) << 16);
            *reinterpret_cast<uint2*>(&my[loff[it]]) = make_uint2(p0, p1);
        }
    }
    // compiler orders ds_write -> ds_read via lgkmcnt (same-wave dependency)

    // ---- Compute: 4 x (16x16) output tiles, 7 MFMA each ----
#pragma unroll
    for (int jo = 0; jo < 4; ++jo) {
        f32x4 acc = {0.f, 0.f, 0.f, 0.f};
#pragma unroll
        for (int dy = 0; dy < 7; ++dy) {
            const int row = l15 + dy;                     // wave-local A row
            const bf16x8 a = *reinterpret_cast<const bf16x8*>(
                &my[row * WSTR + jo * 16 + u0]);          // 16B-aligned b128
            acc = __builtin_amdgcn_mfma_f32_16x16x32_bf16(a, Bf[dy], acc,
                                                          0, 0, 0);
        }
#pragma unroll
        for (int rr = 0; rr < 4; ++rr) {
            const int gr = y0 + lk * 4 + rr;              // D row = lk*4+rr
            on[(size_t)gr * W + x0 + jo * 16 + l15] = acc[rr];
        }
    }
}

extern "C" void kernel_launch(void* const* d_in, const int* in_sizes, int n_in,
                              void* d_out, int out_size, void* d_ws, size_t ws_size,
                              hipStream_t stream) {
    const float* x = (const float*)d_in[0];
    const float* w = (const float*)d_in[1];
    float* out = (float*)d_out;
    bf16x8* bws = (bf16x8*)d_ws;

    build_bfrag<<<1, 64, 0, stream>>>(w, bws);

    const int nblocks = 128 * 64;   // 8192 blocks x 256 threads (4 waves)
    conv7x7_mfma<<<nblocks, 256, 0, stream>>>(x, bws, out);
}